// Round 6
// baseline (136.749 us; speedup 1.0000x reference)
//
#include <hip/hip_runtime.h>
#include <math.h>

// Deepmd angular descriptor, f32 in / f32 out (established rounds 0-4).
// Shapes: B=8, N=4096, M=96, out width 3*N_ANGULAR = 384.
//
// R6 vs R5 (44 us, VALUBusy 29%, HBM 24% -> latency-bound): wave-local
// redesign, zero __syncthreads. Each 64-lane wave owns 2 pairs (32 lanes x
// 3 m's each). Zero-fill of the wave's two output rows issues FIRST (no input
// deps -> 49 MB write stream overlaps all load latency). Cut-exchange via LDS
// within the wave only (lgkmcnt, no barrier). Rare nonzero lanes (~1.3%)
// rank via b128 LDS broadcasts and scatter 12 B straight to global;
// __threadfence_block (in-wave vmcnt drain) orders zero-fill before scatter —
// the same wave owns both stores, so in-wave ordering suffices.
#define M_NB  96
#define OUT_W 384
#define PPBLK 8            // pairs per 256-thread block (N % PPBLK == 0 -> b uniform)

__global__ __launch_bounds__(256) void deepmd_angular_kernel(
    const float* __restrict__ positions,  // [B,N,3]
    const float* __restrict__ cell,       // [B,3,3]
    const float* __restrict__ offsets,    // [B,N,M,3]
    const float* __restrict__ mask,       // [B,N,M]
    const int*   __restrict__ neighbors,  // [B,N,M]
    float*       __restrict__ out,        // [B,N,OUT_W]
    int N)
{
    __shared__ float cut_s[4][2][M_NB];      // [wave][pair-half][m], 3 KB

    const int tid  = threadIdx.x;
    const int wv   = tid >> 6;               // wave in block: 0..3
    const int lane = tid & 63;
    const int h    = lane >> 5;              // which of the wave's 2 pairs
    const int t    = lane & 31;              // lane within pair: m = t + 32*i

    const int pblk = blockIdx.x * PPBLK;
    const int b    = pblk / N;               // uniform per block (N % 8 == 0)
    const int p    = pblk + wv * 2 + h;      // this lane's pair

    // ---- zero-fill this wave's two output rows FIRST (no input deps) ----
    // 2 rows = 768 floats = 192 float4; 64 lanes x 3 coalesced stores.
    float4* orow = (float4*)(out + (size_t)(pblk + wv * 2) * OUT_W);
    const float4 z4 = make_float4(0.f, 0.f, 0.f, 0.f);
    orow[lane]       = z4;
    orow[lane + 64]  = z4;
    orow[lane + 128] = z4;

    // ---- cell (b uniform per block -> scalarizable) ----
    const float* cb = cell + (size_t)b * 9;
    const float c00 = cb[0], c01 = cb[1], c02 = cb[2];
    const float c10 = cb[3], c11 = cb[4], c12 = cb[5];
    const float c20 = cb[6], c21 = cb[7], c22 = cb[8];

    const float pix = positions[(size_t)p * 3 + 0];
    const float piy = positions[(size_t)p * 3 + 1];
    const float piz = positions[(size_t)p * 3 + 2];

    // ---- 3 independent items per thread: maximize outstanding loads ----
    int jn[3]; float mk[3], o0[3], o1[3], o2[3];
    #pragma unroll
    for (int i = 0; i < 3; ++i) {
        const long e = (long)p * M_NB + t + 32 * i;
        jn[i] = neighbors[e];
        mk[i] = mask[e];
        o0[i] = offsets[e * 3 + 0];
        o1[i] = offsets[e * 3 + 1];
        o2[i] = offsets[e * 3 + 2];
    }

    const long posb = (long)b * N * 3;
    float dx[3], dy[3], dz[3], cut[3];
    #pragma unroll
    for (int i = 0; i < 3; ++i) {
        const float* pj = positions + posb + (long)jn[i] * 3;
        dx[i] = pj[0] - pix + o0[i] * c00 + o1[i] * c10 + o2[i] * c20;
        dy[i] = pj[1] - piy + o0[i] * c01 + o1[i] * c11 + o2[i] * c21;
        dz[i] = pj[2] - piz + o0[i] * c02 + o1[i] * c12 + o2[i] * c22;
        const float d = sqrtf(dx[i] * dx[i] + dy[i] * dy[i] + dz[i] * dz[i] + 1e-12f);
        float c = 0.f;
        if (mk[i] != 0.f && d < 6.f)
            c = 0.5f * (cosf(d * 0.52359877559829887f) + 1.f) / d;
        cut[i] = c;
        cut_s[wv][h][t + 32 * i] = c;        // wave-local exchange, no barrier
    }

    // ---- rare path: stable descending rank + 12 B global scatter ----
    // rank(m) = #{k: cut_k > cut_m} + #{k<m: cut_k == cut_m}; zero-cut
    // entries sort after all nonzero ones and write exact zeros -> skip them.
    if (cut[0] != 0.f || cut[1] != 0.f || cut[2] != 0.f) {
        __threadfence_block();               // drain zero-fill stores + LDS writes
        #pragma unroll
        for (int i = 0; i < 3; ++i) {
            if (cut[i] == 0.f) continue;
            const int m = t + 32 * i;
            int rank = 0;
            const float4* c4 = (const float4*)cut_s[wv][h];
            #pragma unroll
            for (int k4 = 0; k4 < M_NB / 4; ++k4) {
                const float4 c = c4[k4];     // ds_read_b128 broadcast
                const int k = 4 * k4;
                rank += (c.x > cut[i]) || (c.x == cut[i] && k + 0 < m);
                rank += (c.y > cut[i]) || (c.y == cut[i] && k + 1 < m);
                rank += (c.z > cut[i]) || (c.z == cut[i] && k + 2 < m);
                rank += (c.w > cut[i]) || (c.w == cut[i] && k + 3 < m);
            }
            float* dst = out + (size_t)p * OUT_W + rank * 3;
            dst[0] = cut[i] * dx[i];
            dst[1] = cut[i] * dy[i];
            dst[2] = cut[i] * dz[i];
        }
    }
}

extern "C" void kernel_launch(void* const* d_in, const int* in_sizes, int n_in,
                              void* d_out, int out_size, void* d_ws, size_t ws_size,
                              hipStream_t stream) {
    const float* positions = (const float*)d_in[0];
    const float* cell      = (const float*)d_in[1];
    const float* offsets   = (const float*)d_in[2];
    const float* mask      = (const float*)d_in[3];
    const int*   neighbors = (const int*)d_in[4];
    float*       out       = (float*)d_out;

    const int BN = in_sizes[0] / 3;        // B*N = 32768
    const int B  = in_sizes[1] / 9;        // 8
    const int N  = BN / B;                 // 4096

    dim3 block(256, 1, 1);
    dim3 grid(BN / PPBLK, 1, 1);           // 4096 blocks
    deepmd_angular_kernel<<<grid, block, 0, stream>>>(
        positions, cell, offsets, mask, neighbors, out, N);
}